// Round 8
// baseline (222.574 us; speedup 1.0000x reference)
//
#include <hip/hip_runtime.h>
#include <hip/hip_fp16.h>

#define S_DIM 512
#define B_DIM 256
#define H_DIM 500
#define M_DIM (S_DIM * B_DIM)     // 131072

typedef _Float16 half8_t __attribute__((ext_vector_type(8)));
typedef float    f32x4  __attribute__((ext_vector_type(4)));

// workspace layout (bytes)
#define WS_W2I 0                       // fp16 image [32][1024][8] = 512 KB (LDS-image order)
#define WS_AT  (512 * 1024)            // fp32 At[h][b] [512][256]   = 512 KB
#define WS_VP  (1024 * 1024)           // fp32 [512]
#define WS_SC  (1024 * 1024 + 4096)    // fp32 [2][256][512] partial scores = 1 MB

__device__ __forceinline__ void gld_lds16(const void* g, void* l) {
    __builtin_amdgcn_global_load_lds(
        (const __attribute__((address_space(1))) unsigned int*)g,
        (__attribute__((address_space(3))) unsigned int*)l, 16, 0, 0);
}

// ---- prep: W2 -> fp16 LDS-image. Plane p = ks*2 + nb (ks = k>>5, nb = n>>8).
// Within plane: slot = nl*4 + cL, cL = ce ^ ((nl>>1)&3)  (verified 0-conflict swizzle),
// 8 halves per slot. Linear gld_lds copy of a plane reproduces swizzled Bs exactly.
__global__ void prep_w2_v(const float* __restrict__ W, const float* __restrict__ v,
                          _Float16* __restrict__ W2i, float* __restrict__ vp) {
    int idx = blockIdx.x * blockDim.x + threadIdx.x;   // 0..131071
#pragma unroll
    for (int r = 0; r < 2; ++r) {
        int e = idx + r * 131072;                      // 0..262143
        int n = e >> 9, k = e & 511;
        float val = (n < H_DIM && k < H_DIM) ? W[n * 1000 + 500 + k] : 0.0f;
        int nb = n >> 8, nl = n & 255, ks = k >> 5, ce = (k >> 3) & 3, u = k & 7;
        int cL = ce ^ ((nl >> 1) & 3);
        W2i[((ks * 2 + nb) * 1024 + nl * 4 + cL) * 8 + u] = (_Float16)val;
    }
    if (idx < 512) vp[idx] = (idx < H_DIM) ? v[idx] : 0.0f;
}

// ---- prep: At[h][b] = b_attn[h] + hidden[b,:] . W1[h,:]  (exact fp32, transposed) ----
__global__ void prep_A(const float* __restrict__ hidden, const float* __restrict__ W,
                       const float* __restrict__ b_attn, float* __restrict__ At) {
    int b = blockIdx.x;
    int t = threadIdx.x;               // 0..511 = h
    __shared__ float hs[512];
    hs[t] = (t < H_DIM) ? hidden[b * H_DIM + t] : 0.0f;
    __syncthreads();
    float acc = 0.0f;
    if (t < H_DIM) {
        acc = b_attn[t];
        const float4* wr = (const float4*)(W + t * 1000);
        const float4* hr = (const float4*)hs;
#pragma unroll 5
        for (int i = 0; i < 125; ++i) {
            float4 w4 = wr[i], h4 = hr[i];
            acc += w4.x * h4.x + w4.y * h4.y + w4.z * h4.z + w4.w * h4.w;
        }
    }
    At[t * B_DIM + b] = acc;
}

// ---- main: BM=128 x BN=256 (N-split 2). 512 thr = 8 waves (2M x 4N), wave 64x64,
// acc[4][4] = 64 AGPR. Arch regs ~55 -> fits 128-unified cap -> 2 blocks/CU, no spill.
// m97 structure: 1 __syncthreads per k-step; B via global_load_lds from pre-swizzled
// image (0 regs); A reg-staged fp32->fp16 (1 slot/thread); no asm pins anywhere.
__launch_bounds__(512, 4)
__global__ void fused_attn_gemm(const float* __restrict__ enc,
                                const _Float16* __restrict__ W2i,
                                const float* __restrict__ At,
                                const float* __restrict__ vp,
                                float* __restrict__ sct) {
    __shared__ _Float16 As[2][128][32];   // 16 KB
    __shared__ _Float16 Bs[2][256][32];   // 32 KB
    __shared__ float    red[4][128];      //  2 KB

    const int tid  = threadIdx.x;
    const int lane = tid & 63;
    const int wid  = tid >> 6;            // 0..7
    const int wm   = wid >> 2;            // 0..1
    const int wn   = wid & 3;             // 0..3
    const int l15  = lane & 15;
    const int lq   = lane >> 4;           // 0..3

    // XCD-chunked swizzle: 2048 blocks = 8 XCDs x 256; n-siblings adjacent on same XCD
    const int wg    = (blockIdx.x & 7) * 256 + (blockIdx.x >> 3);
    const int mblk  = wg >> 1;
    const int nblk  = wg & 1;
    const int m0    = mblk * 128;
    const int s_idx = mblk >> 1;
    const int bloc  = (mblk & 1) * 128;
    const int n0    = nblk * 256;

    // A staging: exactly one (row, chunk) slot per thread
    const int r = tid >> 2;               // 0..127
    const int c = tid & 3;                // 0..3 (8-float chunk)
    const float* gA = enc + (size_t)(m0 + r) * H_DIM + c * 8;
    const int ca = (c ^ ((r >> 1) & 3)) * 8;

    // swizzled fragment-read chunk (constant per lane)
    const int rch = (lq ^ ((l15 >> 1) & 3)) * 8;

    f32x4 a0, a1;                         // pending A slice (next k-step)

    auto ldA = [&](int slice) {
        if (slice < 15) {
            a0 = *(const f32x4*)(gA + slice * 32);
            a1 = *(const f32x4*)(gA + slice * 32 + 4);
        } else {                          // tail: k in [480,512), zero k >= 500
            const float* gr = enc + (size_t)(m0 + r) * H_DIM;
#pragma unroll
            for (int u = 0; u < 4; ++u) {
                int k0 = 480 + c * 8 + u;
                int k1 = k0 + 4;
                a0[u] = (k0 < H_DIM) ? gr[k0] : 0.0f;
                a1[u] = (k1 < H_DIM) ? gr[k1] : 0.0f;
            }
        }
    };
    auto wrA = [&](int buf) {
        half8_t h;
#pragma unroll
        for (int u = 0; u < 4; ++u) { h[u] = (_Float16)a0[u]; h[u + 4] = (_Float16)a1[u]; }
        *(half8_t*)&As[buf][r][ca] = h;
    };
    auto stB = [&](int buf, int ks) {
        const _Float16* pb = W2i + (size_t)(ks * 2 + nblk) * 8192;
        _Float16* dl = (_Float16*)&Bs[buf][0][0] + (size_t)wid * 512;
        gld_lds16(pb + (size_t)tid * 8, dl);
        gld_lds16(pb + (size_t)(tid + 512) * 8, dl + 4096);
    };

    f32x4 acc[4][4];
#pragma unroll
    for (int a = 0; a < 4; ++a)
#pragma unroll
        for (int b = 0; b < 4; ++b) acc[a][b] = 0;

    // prologue: stage k-step 0 into buf 0
    stB(0, 0);
    ldA(0);
    wrA(0);

    for (int ks = 0; ks < 16; ++ks) {
        const int cur = ks & 1;
        __syncthreads();                  // buf[cur] visible; prev reads of buf[cur^1] done
        if (ks < 15) {
            stB(cur ^ 1, ks + 1);         // async B into next buf
            ldA(ks + 1);                  // A loads in flight under compute
        }
        half8_t af[4], bf[4];
#pragma unroll
        for (int mf = 0; mf < 4; ++mf)
            af[mf] = *(const half8_t*)&As[cur][wm * 64 + mf * 16 + l15][rch];
#pragma unroll
        for (int nf = 0; nf < 4; ++nf)
            bf[nf] = *(const half8_t*)&Bs[cur][wn * 64 + nf * 16 + l15][rch];
#pragma unroll
        for (int mf = 0; mf < 4; ++mf)
#pragma unroll
            for (int nf = 0; nf < 4; ++nf)
                acc[mf][nf] = __builtin_amdgcn_mfma_f32_16x16x32_f16(af[mf], bf[nf], acc[mf][nf], 0, 0, 0);
        if (ks < 15) wrA(cur ^ 1);        // cvt + ds_write after MFMAs
    }

    // ---- epilogue: partial scores = sum_h v[h] * tanh(At + E) for this N-half ----
    float vpv[4];
#pragma unroll
    for (int nf = 0; nf < 4; ++nf) vpv[nf] = vp[n0 + wn * 64 + nf * 16 + l15];

    float pj[4][4];
#pragma unroll
    for (int mf = 0; mf < 4; ++mf)
#pragma unroll
        for (int j = 0; j < 4; ++j) pj[mf][j] = 0.0f;

#pragma unroll
    for (int mf = 0; mf < 4; ++mf) {
#pragma unroll
        for (int nf = 0; nf < 4; ++nf) {
            int h = n0 + wn * 64 + nf * 16 + l15;
            f32x4 av = *(const f32x4*)(At + h * B_DIM + bloc + wm * 64 + mf * 16 + lq * 4);
#pragma unroll
            for (int j = 0; j < 4; ++j) {
                float x  = acc[mf][nf][j] + av[j];
                float xc = fminf(fmaxf(x, -9.0f), 9.0f);
                float e  = __expf(2.0f * xc);
                float th = (e - 1.0f) / (e + 1.0f);
                pj[mf][j] += vpv[nf] * th;
            }
        }
    }

#pragma unroll
    for (int mf = 0; mf < 4; ++mf)
#pragma unroll
        for (int j = 0; j < 4; ++j) {
            float s = pj[mf][j];
            s += __shfl_xor(s, 1); s += __shfl_xor(s, 2);
            s += __shfl_xor(s, 4); s += __shfl_xor(s, 8);
            if (l15 == 0) red[wn][wm * 64 + mf * 16 + lq * 4 + j] = s;
        }
    __syncthreads();
    if (tid < 128) {
        float p = red[0][tid] + red[1][tid] + red[2][tid] + red[3][tid];
        sct[(size_t)nblk * M_DIM + (size_t)(bloc + tid) * S_DIM + s_idx] = p;
    }
}

// ---- softmax over S per b, summing the 2 N-partials; out[b][0][s] ----
__global__ void softmax_rows(const float* __restrict__ sct, float* __restrict__ out) {
    int b = blockIdx.x;
    int t = threadIdx.x;                  // 512 threads, one s each
    int lane = t & 63, w = t >> 6;
    size_t idx = (size_t)b * S_DIM + t;
    float v = sct[idx] + sct[idx + M_DIM];
    float m = v;
#pragma unroll
    for (int off = 1; off < 64; off <<= 1) m = fmaxf(m, __shfl_xor(m, off));
    __shared__ float sm[8], ss[8];
    if (lane == 0) sm[w] = m;
    __syncthreads();
    m = sm[0];
#pragma unroll
    for (int i = 1; i < 8; ++i) m = fmaxf(m, sm[i]);
    float e = __expf(v - m);
    float s = e;
#pragma unroll
    for (int off = 1; off < 64; off <<= 1) s += __shfl_xor(s, off);
    if (lane == 0) ss[w] = s;
    __syncthreads();
    s = ss[0];
#pragma unroll
    for (int i = 1; i < 8; ++i) s += ss[i];
    out[(size_t)b * S_DIM + t] = e / s;
}

extern "C" void kernel_launch(void* const* d_in, const int* in_sizes, int n_in,
                              void* d_out, int out_size, void* d_ws, size_t ws_size,
                              hipStream_t stream) {
    const float* hidden = (const float*)d_in[0];
    const float* enc    = (const float*)d_in[1];
    const float* W      = (const float*)d_in[2];
    const float* b_attn = (const float*)d_in[3];
    const float* v      = (const float*)d_in[4];
    float* out = (float*)d_out;

    char* ws = (char*)d_ws;
    _Float16* W2i = (_Float16*)(ws + WS_W2I);
    float*    At  = (float*)(ws + WS_AT);
    float*    vp  = (float*)(ws + WS_VP);
    float*    sct = (float*)(ws + WS_SC);

    prep_w2_v<<<512, 256, 0, stream>>>(W, v, W2i, vp);
    prep_A<<<256, 512, 0, stream>>>(hidden, W, b_attn, At);
    fused_attn_gemm<<<2048, 512, 0, stream>>>(enc, W2i, At, vp, sct);
    softmax_rows<<<256, 512, 0, stream>>>(sct, out);
}

// Round 9
// 208.839 us; speedup vs baseline: 1.0658x; 1.0658x over previous
//
#include <hip/hip_runtime.h>
#include <hip/hip_fp16.h>

#define S_DIM 512
#define B_DIM 256
#define H_DIM 500
#define M_DIM (S_DIM * B_DIM)     // 131072

typedef _Float16 half8_t __attribute__((ext_vector_type(8)));
typedef float    f32x4  __attribute__((ext_vector_type(4)));

// workspace layout (bytes)
#define WS_W2R 0                       // fp16 fragment-tiled [32][64][16][8] = 512 KB
#define WS_AT  (512 * 1024)            // fp32 At[h][b] [512][256]   = 512 KB
#define WS_VP  (1024 * 1024)           // fp32 [512]
#define WS_SC  (1024 * 1024 + 4096)    // fp32 sct[b][s] [256][512]  = 512 KB

// ---- prep: W2 -> fp16, fragment-tiled W2r[t=n>>4][c=k>>3][n&15][k&7]; v padded ----
__global__ void prep_w2_v(const float* __restrict__ W, const float* __restrict__ v,
                          _Float16* __restrict__ W2r, float* __restrict__ vp) {
    int idx = blockIdx.x * blockDim.x + threadIdx.x;   // 0..131071
#pragma unroll
    for (int r = 0; r < 2; ++r) {
        int e = idx + r * 131072;                      // 0..262143
        int n = e >> 9, k = e & 511;
        float val = (n < H_DIM && k < H_DIM) ? W[n * 1000 + 500 + k] : 0.0f;
        int dst = ((n >> 4) * 64 + (k >> 3)) * 128 + (n & 15) * 8 + (k & 7);
        W2r[dst] = (_Float16)val;
    }
    if (idx < 512) vp[idx] = (idx < H_DIM) ? v[idx] : 0.0f;
}

// ---- prep: At[h][b] = b_attn[h] + hidden[b,:] . W1[h,:]  (exact fp32, transposed) ----
__global__ void prep_A(const float* __restrict__ hidden, const float* __restrict__ W,
                       const float* __restrict__ b_attn, float* __restrict__ At) {
    int b = blockIdx.x;
    int t = threadIdx.x;               // 0..511 = h
    __shared__ float hs[512];
    hs[t] = (t < H_DIM) ? hidden[b * H_DIM + t] : 0.0f;
    __syncthreads();
    float acc = 0.0f;
    if (t < H_DIM) {
        acc = b_attn[t];
        const float4* wr = (const float4*)(W + t * 1000);
        const float4* hr = (const float4*)hs;
#pragma unroll 5
        for (int i = 0; i < 125; ++i) {
            float4 w4 = wr[i], h4 = hr[i];
            acc += w4.x * h4.x + w4.y * h4.y + w4.z * h4.z + w4.w * h4.w;
        }
    }
    At[t * B_DIM + b] = acc;
}

// ---- main: BM=64 x full N=512, K=512 in ONE pass.
// Whole A-panel staged to LDS once (64x520 fp16, padded: conflict-free, no swizzle),
// ONE barrier, then a barrier-free k-loop: B global->reg from L2-resident W2r
// (1KB coalesced fragment reads), MFMA. 8 waves = 8 N-slices of 64; wave 64x64,
// acc[4][4]=64 AGPR, arch ~45 -> no spill at the (512,4) 128-reg cap; 2 blocks/CU.
__launch_bounds__(512, 4)
__global__ void fused_attn_gemm(const float* __restrict__ enc,
                                const _Float16* __restrict__ W2r,
                                const float* __restrict__ At,
                                const float* __restrict__ vp,
                                float* __restrict__ sct) {
    __shared__ _Float16 As[64][520];      // 65 KB, padded stride (1040B = 4-bank rotate/row)
    __shared__ float    red[8][64];       //  2 KB

    const int tid  = threadIdx.x;
    const int lane = tid & 63;
    const int wid  = tid >> 6;            // 0..7 = N-slice (64 cols each)
    const int l15  = lane & 15;
    const int lq   = lane >> 4;           // 0..3

    const int mblk  = blockIdx.x;         // 0..2047
    const int m0    = mblk * 64;
    const int s_idx = mblk >> 2;
    const int bbase = (mblk & 3) * 64;    // m = s*256 + b

    // ---- stage whole A panel: thread covers row r, chunks jc, jc+8, ..., jc+56 ----
    {
        const int r  = tid >> 3;          // 0..63
        const int jc = tid & 7;           // 0..7
        const float* gr = enc + (size_t)(m0 + r) * H_DIM;
#pragma unroll
        for (int i = 0; i < 8; ++i) {
            int c = jc + i * 8;           // 0..63 (8 halves each)
            f32x4 v0 = {0, 0, 0, 0}, v1 = {0, 0, 0, 0};
            if (c < 62) {
                v0 = *(const f32x4*)(gr + c * 8);
                v1 = *(const f32x4*)(gr + c * 8 + 4);
            } else if (c == 62) {
                v0 = *(const f32x4*)(gr + 496);   // k 496..499; 500..511 stay zero
            }
            half8_t h;
#pragma unroll
            for (int u = 0; u < 4; ++u) { h[u] = (_Float16)v0[u]; h[u + 4] = (_Float16)v1[u]; }
            *(half8_t*)&As[r][c * 8] = h;
        }
    }
    __syncthreads();                      // the ONLY barrier before the epilogue

    // B fragment base: tile t = wid*4 + nf, chunk c = ks*4 + lq, row l15
    const _Float16* gB = W2r + (size_t)wid * 32768 + lq * 128 + l15 * 8;

    f32x4 acc[4][4];
#pragma unroll
    for (int a = 0; a < 4; ++a)
#pragma unroll
        for (int b = 0; b < 4; ++b) acc[a][b] = 0;

    // ---- barrier-free K loop: 16 steps of K=32 ----
#pragma unroll 2
    for (int ks = 0; ks < 16; ++ks) {
        half8_t bq[4], af[4];
#pragma unroll
        for (int nf = 0; nf < 4; ++nf)
            bq[nf] = *(const half8_t*)(gB + nf * 8192 + ks * 512);
#pragma unroll
        for (int mf = 0; mf < 4; ++mf)
            af[mf] = *(const half8_t*)&As[mf * 16 + l15][(ks * 4 + lq) * 8];
#pragma unroll
        for (int nf = 0; nf < 4; ++nf)
#pragma unroll
            for (int mf = 0; mf < 4; ++mf)
                acc[mf][nf] = __builtin_amdgcn_mfma_f32_16x16x32_f16(af[mf], bq[nf], acc[mf][nf], 0, 0, 0);
    }

    // ---- epilogue: scores = sum_h v[h] * tanh(At + E) ----
    float vpv[4];
#pragma unroll
    for (int nf = 0; nf < 4; ++nf) vpv[nf] = vp[wid * 64 + nf * 16 + l15];

    float pj[4][4];
#pragma unroll
    for (int mf = 0; mf < 4; ++mf)
#pragma unroll
        for (int j = 0; j < 4; ++j) pj[mf][j] = 0.0f;

#pragma unroll
    for (int mf = 0; mf < 4; ++mf) {
#pragma unroll
        for (int nf = 0; nf < 4; ++nf) {
            int h = wid * 64 + nf * 16 + l15;
            f32x4 av = *(const f32x4*)(At + h * B_DIM + bbase + mf * 16 + lq * 4);
#pragma unroll
            for (int j = 0; j < 4; ++j) {
                float x  = acc[mf][nf][j] + av[j];
                float xc = fminf(fmaxf(x, -9.0f), 9.0f);
                float e  = __expf(2.0f * xc);
                float th = (e - 1.0f) / (e + 1.0f);
                pj[mf][j] += vpv[nf] * th;
            }
        }
    }

#pragma unroll
    for (int mf = 0; mf < 4; ++mf)
#pragma unroll
        for (int j = 0; j < 4; ++j) {
            float s = pj[mf][j];
            s += __shfl_xor(s, 1); s += __shfl_xor(s, 2);
            s += __shfl_xor(s, 4); s += __shfl_xor(s, 8);
            if (l15 == 0) red[wid][mf * 16 + lq * 4 + j] = s;
        }
    __syncthreads();
    if (tid < 64) {
        float p = 0.0f;
#pragma unroll
        for (int w = 0; w < 8; ++w) p += red[w][tid];
        sct[(size_t)(bbase + tid) * S_DIM + s_idx] = p;
    }
}

// ---- softmax over S per b; out[b][0][s] ----
__global__ void softmax_rows(const float* __restrict__ sct, float* __restrict__ out) {
    int b = blockIdx.x;
    int t = threadIdx.x;                  // 512 threads, one s each
    int lane = t & 63, w = t >> 6;
    float v = sct[(size_t)b * S_DIM + t];
    float m = v;
#pragma unroll
    for (int off = 1; off < 64; off <<= 1) m = fmaxf(m, __shfl_xor(m, off));
    __shared__ float sm[8], ss[8];
    if (lane == 0) sm[w] = m;
    __syncthreads();
    m = sm[0];
#pragma unroll
    for (int i = 1; i < 8; ++i) m = fmaxf(m, sm[i]);
    float e = __expf(v - m);
    float s = e;
#pragma unroll
    for (int off = 1; off < 64; off <<= 1) s += __shfl_xor(s, off);
    if (lane == 0) ss[w] = s;
    __syncthreads();
    s = ss[0];
#pragma unroll
    for (int i = 1; i < 8; ++i) s += ss[i];
    out[(size_t)b * S_DIM + t] = e / s;
}

extern "C" void kernel_launch(void* const* d_in, const int* in_sizes, int n_in,
                              void* d_out, int out_size, void* d_ws, size_t ws_size,
                              hipStream_t stream) {
    const float* hidden = (const float*)d_in[0];
    const float* enc    = (const float*)d_in[1];
    const float* W      = (const float*)d_in[2];
    const float* b_attn = (const float*)d_in[3];
    const float* v      = (const float*)d_in[4];
    float* out = (float*)d_out;

    char* ws = (char*)d_ws;
    _Float16* W2r = (_Float16*)(ws + WS_W2R);
    float*    At  = (float*)(ws + WS_AT);
    float*    vp  = (float*)(ws + WS_VP);
    float*    sct = (float*)(ws + WS_SC);

    prep_w2_v<<<512, 256, 0, stream>>>(W, v, W2r, vp);
    prep_A<<<256, 512, 0, stream>>>(hidden, W, b_attn, At);
    fused_attn_gemm<<<2048, 512, 0, stream>>>(enc, W2r, At, vp, sct);
    softmax_rows<<<256, 512, 0, stream>>>(sct, out);
}

// Round 10
// 207.166 us; speedup vs baseline: 1.0744x; 1.0081x over previous
//
#include <hip/hip_runtime.h>
#include <hip/hip_fp16.h>

#define S_DIM 512
#define B_DIM 256
#define H_DIM 500
#define M_DIM (S_DIM * B_DIM)     // 131072

typedef _Float16 half8_t __attribute__((ext_vector_type(8)));
typedef float    f32x4  __attribute__((ext_vector_type(4)));

// workspace layout (bytes)
#define WS_W2R 0                       // fp16 fragment-tiled [32][64][16][8] = 512 KB
#define WS_AT  (512 * 1024)            // fp32 At[h][b] [512][256]   = 512 KB
#define WS_VP  (1024 * 1024)           // fp32 [512]
#define WS_SC  (1024 * 1024 + 4096)    // fp32 sct[b][s] [256][512]  = 512 KB

// ---- prep: W2 -> fp16, fragment-tiled W2r[t=n>>4][c=k>>3][n&15][k&7]; v padded ----
__global__ void prep_w2_v(const float* __restrict__ W, const float* __restrict__ v,
                          _Float16* __restrict__ W2r, float* __restrict__ vp) {
    int idx = blockIdx.x * blockDim.x + threadIdx.x;   // 0..131071
#pragma unroll
    for (int r = 0; r < 2; ++r) {
        int e = idx + r * 131072;                      // 0..262143
        int n = e >> 9, k = e & 511;
        float val = (n < H_DIM && k < H_DIM) ? W[n * 1000 + 500 + k] : 0.0f;
        int dst = ((n >> 4) * 64 + (k >> 3)) * 128 + (n & 15) * 8 + (k & 7);
        W2r[dst] = (_Float16)val;
    }
    if (idx < 512) vp[idx] = (idx < H_DIM) ? v[idx] : 0.0f;
}

// ---- prep: At[h][b] = b_attn[h] + hidden[b,:] . W1[h,:]  (exact fp32, transposed) ----
__global__ void prep_A(const float* __restrict__ hidden, const float* __restrict__ W,
                       const float* __restrict__ b_attn, float* __restrict__ At) {
    int b = blockIdx.x;
    int t = threadIdx.x;               // 0..511 = h
    __shared__ float hs[512];
    hs[t] = (t < H_DIM) ? hidden[b * H_DIM + t] : 0.0f;
    __syncthreads();
    float acc = 0.0f;
    if (t < H_DIM) {
        acc = b_attn[t];
        const float4* wr = (const float4*)(W + t * 1000);
        const float4* hr = (const float4*)hs;
#pragma unroll 5
        for (int i = 0; i < 125; ++i) {
            float4 w4 = wr[i], h4 = hr[i];
            acc += w4.x * h4.x + w4.y * h4.y + w4.z * h4.z + w4.w * h4.w;
        }
    }
    At[t * B_DIM + b] = acc;
}

// ---- main: BM=64 x full N=512, K=512 in ONE pass.
// Whole A-panel staged to LDS once (64x512 fp16, XOR-swizzled chunk c -> c^(r&7):
// verified distinct banks per 8-lane group => 0 conflicts), ONE barrier, then a
// barrier-free k-loop: B global->reg from L2-resident W2r (1KB coalesced fragment
// reads), MFMA. 8 waves = 8 N-slices; wave 64x64, acc[4][4].
// __launch_bounds__(512) => 256-reg cap: demand ~150, NO spill (the R9 killer).
__launch_bounds__(512)
__global__ void fused_attn_gemm(const float* __restrict__ enc,
                                const _Float16* __restrict__ W2r,
                                const float* __restrict__ At,
                                const float* __restrict__ vp,
                                float* __restrict__ sct) {
    __shared__ _Float16 As[64][512];      // 64 KB, swizzled
    __shared__ float    red[8][64];       //  2 KB

    const int tid  = threadIdx.x;
    const int lane = tid & 63;
    const int wid  = tid >> 6;            // 0..7 = N-slice (64 cols each)
    const int l15  = lane & 15;
    const int lq   = lane >> 4;           // 0..3

    const int mblk  = blockIdx.x;         // 0..2047
    const int m0    = mblk * 64;
    const int s_idx = mblk >> 2;
    const int bbase = (mblk & 3) * 64;    // m = s*256 + b

    // ---- stage whole A panel: thread covers row r, chunks jc, jc+8, ..., jc+56 ----
    {
        const int r  = tid >> 3;          // 0..63
        const int jc = tid & 7;           // 0..7
        const float* gr = enc + (size_t)(m0 + r) * H_DIM;
#pragma unroll
        for (int i = 0; i < 8; ++i) {
            int c = jc + i * 8;           // 0..63 (8 halves each)
            f32x4 v0 = {0, 0, 0, 0}, v1 = {0, 0, 0, 0};
            if (c < 62) {
                v0 = *(const f32x4*)(gr + c * 8);
                v1 = *(const f32x4*)(gr + c * 8 + 4);
            } else if (c == 62) {
                v0 = *(const f32x4*)(gr + 496);   // k 496..499; 500..511 stay zero
            }
            half8_t h;
#pragma unroll
            for (int u = 0; u < 4; ++u) { h[u] = (_Float16)v0[u]; h[u + 4] = (_Float16)v1[u]; }
            *(half8_t*)&As[r][(c ^ (r & 7)) * 8] = h;   // XOR-swizzled chunk
        }
    }
    __syncthreads();                      // the ONLY barrier before the epilogue

    // B fragment base: tile t = wid*4 + nf, chunk c = ks*4 + lq, row l15
    const _Float16* gB = W2r + (size_t)wid * 32768 + lq * 128 + l15 * 8;

    f32x4 acc[4][4];
#pragma unroll
    for (int a = 0; a < 4; ++a)
#pragma unroll
        for (int b = 0; b < 4; ++b) acc[a][b] = 0;

    const int swz = (l15 & 7);            // read-side XOR (row&7 == l15&7 for 16-mult rows)

    // ---- barrier-free K loop: 16 steps of K=32; unroll 4 lets compiler pipeline B loads
#pragma unroll 4
    for (int ks = 0; ks < 16; ++ks) {
        half8_t bq[4], af[4];
#pragma unroll
        for (int nf = 0; nf < 4; ++nf)
            bq[nf] = *(const half8_t*)(gB + nf * 8192 + ks * 512);
#pragma unroll
        for (int mf = 0; mf < 4; ++mf)
            af[mf] = *(const half8_t*)&As[mf * 16 + l15][((ks * 4 + lq) ^ swz) * 8];
#pragma unroll
        for (int nf = 0; nf < 4; ++nf)
#pragma unroll
            for (int mf = 0; mf < 4; ++mf)
                acc[mf][nf] = __builtin_amdgcn_mfma_f32_16x16x32_f16(af[mf], bq[nf], acc[mf][nf], 0, 0, 0);
    }

    // ---- epilogue: scores = sum_h v[h] * tanh(At + E) ----
    float vpv[4];
#pragma unroll
    for (int nf = 0; nf < 4; ++nf) vpv[nf] = vp[wid * 64 + nf * 16 + l15];

    float pj[4][4];
#pragma unroll
    for (int mf = 0; mf < 4; ++mf)
#pragma unroll
        for (int j = 0; j < 4; ++j) pj[mf][j] = 0.0f;

#pragma unroll
    for (int mf = 0; mf < 4; ++mf) {
#pragma unroll
        for (int nf = 0; nf < 4; ++nf) {
            int h = wid * 64 + nf * 16 + l15;
            f32x4 av = *(const f32x4*)(At + h * B_DIM + bbase + mf * 16 + lq * 4);
#pragma unroll
            for (int j = 0; j < 4; ++j) {
                float x  = acc[mf][nf][j] + av[j];
                float xc = fminf(fmaxf(x, -9.0f), 9.0f);
                float e  = __expf(2.0f * xc);
                float th = (e - 1.0f) / (e + 1.0f);
                pj[mf][j] += vpv[nf] * th;
            }
        }
    }

#pragma unroll
    for (int mf = 0; mf < 4; ++mf)
#pragma unroll
        for (int j = 0; j < 4; ++j) {
            float s = pj[mf][j];
            s += __shfl_xor(s, 1); s += __shfl_xor(s, 2);
            s += __shfl_xor(s, 4); s += __shfl_xor(s, 8);
            if (l15 == 0) red[wid][mf * 16 + lq * 4 + j] = s;
        }
    __syncthreads();
    if (tid < 64) {
        float p = 0.0f;
#pragma unroll
        for (int w = 0; w < 8; ++w) p += red[w][tid];
        sct[(size_t)(bbase + tid) * S_DIM + s_idx] = p;
    }
}

// ---- softmax over S per b; out[b][0][s] ----
__global__ void softmax_rows(const float* __restrict__ sct, float* __restrict__ out) {
    int b = blockIdx.x;
    int t = threadIdx.x;                  // 512 threads, one s each
    int lane = t & 63, w = t >> 6;
    float v = sct[(size_t)b * S_DIM + t];
    float m = v;
#pragma unroll
    for (int off = 1; off < 64; off <<= 1) m = fmaxf(m, __shfl_xor(m, off));
    __shared__ float sm[8], ss[8];
    if (lane == 0) sm[w] = m;
    __syncthreads();
    m = sm[0];
#pragma unroll
    for (int i = 1; i < 8; ++i) m = fmaxf(m, sm[i]);
    float e = __expf(v - m);
    float s = e;
#pragma unroll
    for (int off = 1; off < 64; off <<= 1) s += __shfl_xor(s, off);
    if (lane == 0) ss[w] = s;
    __syncthreads();
    s = ss[0];
#pragma unroll
    for (int i = 1; i < 8; ++i) s += ss[i];
    out[(size_t)b * S_DIM + t] = e / s;
}

extern "C" void kernel_launch(void* const* d_in, const int* in_sizes, int n_in,
                              void* d_out, int out_size, void* d_ws, size_t ws_size,
                              hipStream_t stream) {
    const float* hidden = (const float*)d_in[0];
    const float* enc    = (const float*)d_in[1];
    const float* W      = (const float*)d_in[2];
    const float* b_attn = (const float*)d_in[3];
    const float* v      = (const float*)d_in[4];
    float* out = (float*)d_out;

    char* ws = (char*)d_ws;
    _Float16* W2r = (_Float16*)(ws + WS_W2R);
    float*    At  = (float*)(ws + WS_AT);
    float*    vp  = (float*)(ws + WS_VP);
    float*    sct = (float*)(ws + WS_SC);

    prep_w2_v<<<512, 256, 0, stream>>>(W, v, W2r, vp);
    prep_A<<<256, 512, 0, stream>>>(hidden, W, b_attn, At);
    fused_attn_gemm<<<2048, 512, 0, stream>>>(enc, W2r, At, vp, sct);
    softmax_rows<<<256, 512, 0, stream>>>(sct, out);
}